// Round 1
// baseline (149.117 us; speedup 1.0000x reference)
//
#include <hip/hip_runtime.h>
#include <math.h>

#define B_    32
#define L_    16384
#define C_    128
#define KTOP  64
#define NCOL  (B_ * C_)      // 4096 columns
#define SORTN 512            // bitonic sort width (power of 2, >= cap)
#define T0    2.25f          // filter threshold; E[count>T0] ~ 200 per column

// lexicographic (value, index) less-than
__device__ __forceinline__ bool lex_lt(float v1, int i1, float v2, int i2) {
    return (v1 < v2) || ((v1 == v2) && (i1 < i2));
}

__device__ __forceinline__ void push_cand(int col, int l, float v,
                                          int* __restrict__ cnt,
                                          float* __restrict__ cval,
                                          int* __restrict__ cidx, int cap) {
    int p = atomicAdd(&cnt[col], 1);
    if (p < cap) {
        size_t o = (size_t)col * cap + p;
        cval[o] = v;
        cidx[o] = l;
    }
}

// Pass 1: stream all of x (coalesced float4), compact values > T0 per column.
// grid: (L_/256, B_), block: 256 threads (8 rows x 32 float4-lanes)
__global__ __launch_bounds__(256) void k_filter(const float* __restrict__ x,
                                                int* __restrict__ cnt,
                                                float* __restrict__ cval,
                                                int* __restrict__ cidx,
                                                int cap) {
    const int b  = blockIdx.y;
    const int l0 = blockIdx.x * 256;
    const int r  = threadIdx.x >> 5;     // 0..7 row within group
    const int c4 = threadIdx.x & 31;     // float4 slot within row (0..31)
    const float4* xb = (const float4*)x + (size_t)b * L_ * (C_ / 4);
    const int cbase = b * C_ + c4 * 4;

    for (int l = l0 + r; l < l0 + 256; l += 8) {
        float4 v = xb[(size_t)l * (C_ / 4) + c4];
        if (v.x > T0) push_cand(cbase + 0, l, v.x, cnt, cval, cidx, cap);
        if (v.y > T0) push_cand(cbase + 1, l, v.y, cnt, cval, cidx, cap);
        if (v.z > T0) push_cand(cbase + 2, l, v.z, cnt, cval, cidx, cap);
        if (v.w > T0) push_cand(cbase + 3, l, v.w, cnt, cval, cidx, cap);
    }
}

// Pass 2: one block per column. Fast path: bitonic-sort candidates desc by
// (value, index) -- matches JAX stable-argsort tie rule (largest indices kept
// among equal values) -- take top-64, rank by index, scatter.
// Fallback (count < 64 or overflow): exact 64-round lexicographic descent.
__global__ __launch_bounds__(256) void k_select(const float* __restrict__ x,
                                                const int* __restrict__ cnt,
                                                const float* __restrict__ cval,
                                                const int* __restrict__ cidx,
                                                float* __restrict__ out,
                                                int cap) {
    __shared__ float sv[SORTN];
    __shared__ int   si[SORTN];
    __shared__ float rv[256];
    __shared__ int   ri[256];
    __shared__ float ov[KTOP];
    __shared__ int   oi[KTOP];

    const int col = blockIdx.x;
    const int b   = col >> 7;
    const int c   = col & (C_ - 1);
    const int tid = threadIdx.x;

    const int n = (cap > 0) ? cnt[col] : 0;

    if (n >= KTOP && n <= cap) {
        // ---- fast path ----
        for (int i = tid; i < SORTN; i += 256) {
            if (i < n) {
                size_t o = (size_t)col * cap + i;
                sv[i] = cval[o];
                si[i] = cidx[o];
            } else {
                sv[i] = -INFINITY;
                si[i] = -1;
            }
        }
        __syncthreads();
        // bitonic sort, descending by (value, index)
        for (int k = 2; k <= SORTN; k <<= 1) {
            for (int j = k >> 1; j > 0; j >>= 1) {
                for (int i = tid; i < SORTN; i += 256) {
                    int ixj = i ^ j;
                    if (ixj > i) {
                        bool up = ((i & k) == 0);
                        if (lex_lt(sv[i], si[i], sv[ixj], si[ixj]) == up) {
                            float tv = sv[i]; sv[i] = sv[ixj]; sv[ixj] = tv;
                            int   ti = si[i]; si[i] = si[ixj]; si[ixj] = ti;
                        }
                    }
                }
                __syncthreads();
            }
        }
        // rank the top-64 by original index to restore temporal order
        if (tid < KTOP) {
            int   my = si[tid];
            float v  = sv[tid];
            int rank = 0;
            for (int j = 0; j < KTOP; ++j) rank += (si[j] < my);
            out[((size_t)b * KTOP + rank) * C_ + c] = v;
        }
    } else {
        // ---- exact fallback: lexicographic-descent argmax, 64 rounds ----
        const float* xc = x + (size_t)b * L_ * C_ + c;
        float pv = INFINITY;
        int   pi = 0x7fffffff;
        for (int k = 0; k < KTOP; ++k) {
            float bv = -INFINITY;
            int   bi = -1;
            for (int l = tid; l < L_; l += 256) {
                float v = xc[(size_t)l * C_];
                if (lex_lt(v, l, pv, pi) && lex_lt(bv, bi, v, l)) {
                    bv = v; bi = l;
                }
            }
            rv[tid] = bv; ri[tid] = bi;
            __syncthreads();
            for (int s = 128; s > 0; s >>= 1) {
                if (tid < s) {
                    if (lex_lt(rv[tid], ri[tid], rv[tid + s], ri[tid + s])) {
                        rv[tid] = rv[tid + s]; ri[tid] = ri[tid + s];
                    }
                }
                __syncthreads();
            }
            pv = rv[0]; pi = ri[0];
            if (tid == 0) { ov[k] = pv; oi[k] = pi; }
            __syncthreads();
        }
        if (tid < KTOP) {
            int my = oi[tid];
            int rank = 0;
            for (int j = 0; j < KTOP; ++j) rank += (oi[j] < my);
            out[((size_t)b * KTOP + rank) * C_ + c] = ov[tid];
        }
    }
}

extern "C" void kernel_launch(void* const* d_in, const int* in_sizes, int n_in,
                              void* d_out, int out_size, void* d_ws, size_t ws_size,
                              hipStream_t stream) {
    (void)in_sizes; (void)n_in; (void)out_size;
    const float* x  = (const float*)d_in[0];
    float*      out = (float*)d_out;

    int*   cnt       = (int*)d_ws;
    size_t cnt_bytes = (size_t)NCOL * sizeof(int);

    // size the candidate buffers from the workspace we actually have
    int cap = 0;
    if (ws_size > cnt_bytes) {
        size_t rem = ws_size - cnt_bytes;
        size_t c   = rem / ((size_t)NCOL * 8);  // 4B val + 4B idx per slot
        cap = (c > SORTN) ? SORTN : (int)c;
    }
    float* cval = (float*)((char*)d_ws + cnt_bytes);
    int*   cidx = (int*)((char*)d_ws + cnt_bytes + (size_t)NCOL * cap * sizeof(float));

    if (cap >= KTOP) {
        hipMemsetAsync(cnt, 0, cnt_bytes, stream);
        dim3 g1(L_ / 256, B_);
        k_filter<<<g1, 256, 0, stream>>>(x, cnt, cval, cidx, cap);
    } else {
        cap = 0;  // workspace too small: k_select takes exact fallback for all columns
    }

    k_select<<<NCOL, 256, 0, stream>>>(x, cnt, cval, cidx, out, cap);
}